// Round 10
// baseline (95.469 us; speedup 1.0000x reference)
//
#include <hip/hip_runtime.h>
#include <hip/hip_bf16.h>

typedef __bf16 bf16x8 __attribute__((ext_vector_type(8)));
typedef float  f32x4  __attribute__((ext_vector_type(4)));
typedef float  f32x2  __attribute__((ext_vector_type(2)));

#define B_  32
#define J_  143
#define F_  120
#define D_  256
#define L_  512
#define C_  13
#define M_  4576      // B_*J_
#define MP_ 4736      // padded rows (74*64), fe rows live at 4576..4695
#define FE0 4576
#define NK  512       // K = [hi(256) | lo(256)]
#define NN  384       // N = [Wg1c(256) | feT(120) | pad(8)]

static __device__ __forceinline__ unsigned short bits(__bf16 h) {
  return __builtin_bit_cast(unsigned short, h);
}

// packed tanh-GELU (ln2 folded): u * rcp(1 + exp2(u*(c1 + c2*u^2)))
__device__ __forceinline__ f32x2 gelu2(f32x2 u) {
  f32x2 x2 = u * u;
  f32x2 t  = u * (x2 * -0.1029432f + -2.3022082f);
  f32x2 e;
  e.x = __builtin_amdgcn_exp2f(t.x);
  e.y = __builtin_amdgcn_exp2f(t.y);
  f32x2 d = e + 1.0f;
  f32x2 r;
  r.x = __builtin_amdgcn_rcpf(d.x);
  r.y = __builtin_amdgcn_rcpf(d.y);
  return u * r;
}

// ---------- prep: grid 157 ----------
// [0,32): base=z@Wl+bl
// [32,36): BT col-group (64 cols each), coalesced two-pass
// [36,156): fe row f -> BT col 256+f, Sfe, Sfe2
// 156: pad cols 376..384, W2T, zerov
__global__ __launch_bounds__(256) void prep_kernel(
    const float* __restrict__ z, const float* __restrict__ Wl,
    const float* __restrict__ bl, const float* __restrict__ W1,
    const float* __restrict__ gamma, const float* __restrict__ beta,
    const float* __restrict__ b1, const float* __restrict__ fe,
    const float* __restrict__ W2,
    float* __restrict__ base, unsigned short* __restrict__ BT,
    float* __restrict__ bW1, float* __restrict__ Sfe, float* __restrict__ Sfe2,
    unsigned short* __restrict__ W2T, float* __restrict__ zerov) {
  const int t = threadIdx.x, bid = blockIdx.x;
  const int lane = t & 63, wv = t >> 6;
  __shared__ float zs[L_];
  __shared__ float ra[4], rb[4];
  __shared__ float gml[256], btl[256];
  __shared__ float redg[4][64], redb[4][64];
  __shared__ float csl[64];

  if (bid < 32) {
    zs[t]       = z[bid * L_ + t];
    zs[t + 256] = z[bid * L_ + t + 256];
    __syncthreads();
    float acc = 0.f;
    #pragma unroll 32
    for (int k = 0; k < L_; ++k) acc = __builtin_fmaf(zs[k], Wl[k * D_ + t], acc);
    base[bid * D_ + t] = acc + bl[t];
    return;
  }
  if (bid < 36) {
    // 64-column group, coalesced
    const int n0 = (bid - 32) * 64;
    const int c  = t & 63;          // column within group
    const int kg = t >> 6;          // k quarter
    gml[t] = gamma[t];
    btl[t] = beta[t];
    __syncthreads();
    float wg = 0.f, wb = 0.f;
    #pragma unroll 16
    for (int kk = 0; kk < 64; ++kk) {
      const int k = kg * 64 + kk;
      const float w1v = W1[k * D_ + n0 + c];   // coalesced 64-wide
      wg = __builtin_fmaf(gml[k], w1v, wg);
      wb = __builtin_fmaf(btl[k], w1v, wb);
    }
    redg[kg][c] = wg;
    redb[kg][c] = wb;
    __syncthreads();
    if (t < 64) {
      const float cs = redg[0][t] + redg[1][t] + redg[2][t] + redg[3][t];
      const float bs = redb[0][t] + redb[1][t] + redb[2][t] + redb[3][t];
      csl[t] = cs * (1.f / 256.f);
      bW1[n0 + t] = bs + b1[n0 + t];
    }
    __syncthreads();
    const float csc = csl[c];
    #pragma unroll 16
    for (int kk = 0; kk < 64; ++kk) {
      const int k = kg * 64 + kk;
      const float w1v = W1[k * D_ + n0 + c];
      const float m = __builtin_fmaf(gml[k], w1v, -csc);
      const __bf16 hi = (__bf16)m;
      const __bf16 lo = (__bf16)(m - (float)hi);
      BT[(n0 + c) * NK + k]       = bits(hi);
      BT[(n0 + c) * NK + 256 + k] = bits(lo);
    }
    return;
  }
  if (bid < 156) {
    const int f = bid - 36;
    const float v = fe[f * D_ + t];
    float a = v, b = v * v;
    #pragma unroll
    for (int m = 1; m < 64; m <<= 1) { a += __shfl_xor(a, m); b += __shfl_xor(b, m); }
    if (lane == 0) { ra[wv] = a; rb[wv] = b; }
    __syncthreads();
    if (t == 0) {
      Sfe[f]  = ra[0] + ra[1] + ra[2] + ra[3];
      Sfe2[f] = rb[0] + rb[1] + rb[2] + rb[3];
    }
    const __bf16 hi = (__bf16)v;
    const __bf16 lo = (__bf16)(v - (float)hi);
    BT[(256 + f) * NK + t]       = bits(hi);
    BT[(256 + f) * NK + 256 + t] = bits(lo);
    return;
  }
  // bid == 156: pads + W2T + zerov
  #pragma unroll
  for (int i = 0; i < 16; ++i)
    BT[376 * NK + i * 256 + t] = 0;   // 8 cols x 512 entries = 4096 shorts
  #pragma unroll
  for (int c = 0; c < 16; ++c) {
    const float v = (c < C_) ? W2[t * C_ + c] : 0.f;
    W2T[c * D_ + t] = bits((__bf16)v);
  }
  zerov[t] = 0.f;
}

// ---------- gemmB: PX[MP_ x NN] = A @ B, 64x64 tiles (444 blocks) ----------
__global__ __launch_bounds__(256, 4) void gemmB_kernel(
    const float* __restrict__ base, const float* __restrict__ joint,
    const float* __restrict__ fe, const float* __restrict__ zerov,
    const unsigned short* __restrict__ BT,
    float* __restrict__ PX, float* __restrict__ Sc, float* __restrict__ Sc2) {
  const int tid = threadIdx.x, lane = tid & 63, wave = tid >> 6;
  const int lrow = lane & 15, lgrp = lane >> 4;
  const int rb_ = blockIdx.x / 6, cb_ = blockIdx.x % 6;
  const int rowbase = rb_ * 64 + wave * 16;
  const int colbase = cb_ * 64;
  const int r = rowbase + lrow;

  const float *p1, *p2;
  if (r < M_) {
    const int b = r / J_, j = r - b * J_;
    p1 = base + b * D_; p2 = joint + j * D_;
  } else if (r < FE0 + F_) {
    p1 = fe + (r - FE0) * D_; p2 = zerov;
  } else {
    p1 = zerov; p2 = zerov;
  }

  const unsigned short* Bp = BT + (size_t)(colbase + lrow) * NK + lgrp * 8;
  f32x4 acc[4] = {};
  float ssum = 0.f, ssq = 0.f;
  #pragma unroll
  for (int s8 = 0; s8 < 8; ++s8) {
    const int k0 = s8 * 32 + lgrp * 8;
    const float4 ca = *(const float4*)(p1 + k0);
    const float4 cb4 = *(const float4*)(p1 + k0 + 4);
    const float4 da = *(const float4*)(p2 + k0);
    const float4 db = *(const float4*)(p2 + k0 + 4);
    const float c[8] = {ca.x + da.x, ca.y + da.y, ca.z + da.z, ca.w + da.w,
                        cb4.x + db.x, cb4.y + db.y, cb4.z + db.z, cb4.w + db.w};
    bf16x8 ahi, alo;
    #pragma unroll
    for (int e = 0; e < 8; ++e) {
      const __bf16 h = (__bf16)c[e];
      ahi[e] = h;
      alo[e] = (__bf16)(c[e] - (float)h);
    }
    if (cb_ == 0) {
      #pragma unroll
      for (int e = 0; e < 8; ++e) { ssum += c[e]; ssq = __builtin_fmaf(c[e], c[e], ssq); }
    }
    bf16x8 bhi[4], blo[4];
    #pragma unroll
    for (int nf = 0; nf < 4; ++nf) {
      bhi[nf] = *(const bf16x8*)(Bp + (size_t)nf * 16 * NK + s8 * 32);
      blo[nf] = *(const bf16x8*)(Bp + (size_t)nf * 16 * NK + 256 + s8 * 32);
    }
    #pragma unroll
    for (int nf = 0; nf < 4; ++nf)
      acc[nf] = __builtin_amdgcn_mfma_f32_16x16x32_bf16(ahi, bhi[nf], acc[nf], 0, 0, 0);
    #pragma unroll
    for (int nf = 0; nf < 4; ++nf)
      acc[nf] = __builtin_amdgcn_mfma_f32_16x16x32_bf16(alo, bhi[nf], acc[nf], 0, 0, 0);
    #pragma unroll
    for (int nf = 0; nf < 4; ++nf)
      acc[nf] = __builtin_amdgcn_mfma_f32_16x16x32_bf16(ahi, blo[nf], acc[nf], 0, 0, 0);
  }

  if (cb_ == 0) {
    ssum += __shfl_xor(ssum, 16); ssum += __shfl_xor(ssum, 32);
    ssq  += __shfl_xor(ssq, 16);  ssq  += __shfl_xor(ssq, 32);
    if (lgrp == 0) { Sc[r] = ssum; Sc2[r] = ssq; }
  }

  #pragma unroll
  for (int nf = 0; nf < 4; ++nf)
    #pragma unroll
    for (int r4 = 0; r4 < 4; ++r4)
      PX[(size_t)(rowbase + lgrp * 4 + r4) * NN + colbase + nf * 16 + lrow] = acc[nf][r4];
}

// ---------- mainC: 4 bj per block (1144 blocks); packed gelu; GEMM2; direct stores ----
__global__ __launch_bounds__(256, 4) void mainC_kernel(
    const float* __restrict__ PX, const float* __restrict__ bW1,
    const float* __restrict__ Sc, const float* __restrict__ Sc2,
    const float* __restrict__ Sfe, const float* __restrict__ Sfe2,
    const unsigned short* __restrict__ W2T, const float* __restrict__ b2,
    float* __restrict__ out) {
  __shared__ float pc[4][256], bw[256], rstdl[4][128];
  __shared__ __align__(16) unsigned short w2l[4096];   // 16x256 bf16, XOR-swizzled
  const int tid = threadIdx.x, lane = tid & 63, wv = tid >> 6;
  const int lrow = lane & 15, lgrp = lane >> 4;
  const int bj0 = blockIdx.x * 4;

  #pragma unroll
  for (int q = 0; q < 4; ++q) pc[q][tid] = PX[(size_t)(bj0 + q) * NN + tid];
  bw[tid] = bW1[tid];
  {
    const int rr = tid >> 4;
    const int b0 = tid * 32;
    const int sb = b0 ^ ((rr & 7) << 4);
    *(uint4*)((char*)w2l + sb)        = *(const uint4*)((const char*)W2T + b0);
    *(uint4*)((char*)w2l + (sb ^ 16)) = *(const uint4*)((const char*)W2T + b0 + 16);
  }
  #pragma unroll
  for (int qq = 0; qq < 2; ++qq) {
    const int idx = tid + qq * 256;
    const int q = idx >> 7;
    const int f = idx & 127;
    const int fc = f < F_ ? f : F_ - 1;
    const float X = PX[(size_t)(bj0 + q) * NN + 256 + fc];
    const float mu = (Sc[bj0 + q] + Sfe[fc]) * (1.f / 256.f);
    const float ms = __builtin_fmaf(2.f, X, Sc2[bj0 + q] + Sfe2[fc]) * (1.f / 256.f);
    rstdl[q][f] = rsqrtf(ms - mu * mu + 1e-5f);
  }
  __syncthreads();

  const int r0 = wv * 32 + lrow, r1 = r0 + 16;
  const int f0 = r0 < F_ ? r0 : F_ - 1;
  const int f1 = r1 < F_ ? r1 : F_ - 1;
  float rs0[4], rs1[4];
  #pragma unroll
  for (int q = 0; q < 4; ++q) { rs0[q] = rstdl[q][r0]; rs1[q] = rstdl[q][r1]; }
  const float* __restrict__ q0p = PX + (size_t)(FE0 + f0) * NN + lgrp * 8;
  const float* __restrict__ q1p = PX + (size_t)(FE0 + f1) * NN + lgrp * 8;

  // 1-ahead f32 q prefetch
  float4 qa0 = *(const float4*)(q0p), qa1 = *(const float4*)(q0p + 4);
  float4 qb0 = *(const float4*)(q1p), qb1 = *(const float4*)(q1p + 4);

  f32x4 acc[4][2] = {};
  #pragma unroll
  for (int s = 0; s < 8; ++s) {
    const int n0 = s * 32 + lgrp * 8;
    float4 na0, na1, nb0, nb1;
    if (s < 7) {
      na0 = *(const float4*)(q0p + (s + 1) * 32);
      na1 = *(const float4*)(q0p + (s + 1) * 32 + 4);
      nb0 = *(const float4*)(q1p + (s + 1) * 32);
      nb1 = *(const float4*)(q1p + (s + 1) * 32 + 4);
    }
    const bf16x8 w2f = *(const bf16x8*)((const char*)w2l +
        ((lrow * 512 + n0 * 2) ^ ((lrow & 7) << 4)));
    const float q0v[8] = {qa0.x, qa0.y, qa0.z, qa0.w, qa1.x, qa1.y, qa1.z, qa1.w};
    const float q1v[8] = {qb0.x, qb0.y, qb0.z, qb0.w, qb1.x, qb1.y, qb1.z, qb1.w};
    #pragma unroll
    for (int q = 0; q < 4; ++q) {
      bf16x8 af0, af1;
      #pragma unroll
      for (int ep = 0; ep < 4; ++ep) {
        const int e0 = 2 * ep;
        f32x2 Q0, Q1, BV;
        Q0.x = q0v[e0]; Q0.y = q0v[e0 + 1];
        Q1.x = q1v[e0]; Q1.y = q1v[e0 + 1];
        BV = *(const f32x2*)(&bw[n0 + e0]);
        const f32x2 P = *(const f32x2*)(&pc[q][n0 + e0]);
        f32x2 RS0; RS0.x = rs0[q]; RS0.y = rs0[q];
        f32x2 RS1; RS1.x = rs1[q]; RS1.y = rs1[q];
        const f32x2 U0 = __builtin_elementwise_fma(RS0, P + Q0, BV);
        const f32x2 U1 = __builtin_elementwise_fma(RS1, P + Q1, BV);
        const f32x2 G0 = gelu2(U0);
        const f32x2 G1 = gelu2(U1);
        af0[e0] = (__bf16)G0.x; af0[e0 + 1] = (__bf16)G0.y;
        af1[e0] = (__bf16)G1.x; af1[e0 + 1] = (__bf16)G1.y;
      }
      acc[q][0] = __builtin_amdgcn_mfma_f32_16x16x32_bf16(af0, w2f, acc[q][0], 0, 0, 0);
      acc[q][1] = __builtin_amdgcn_mfma_f32_16x16x32_bf16(af1, w2f, acc[q][1], 0, 0, 0);
    }
    qa0 = na0; qa1 = na1; qb0 = nb0; qb1 = nb1;
  }

  // direct epilogue: acc[q][mf][r4] is (c=lrow, f=wv*32+mf*16+lgrp*4+r4)
  if (lrow < C_) {
    const float bias = b2[lrow];
    #pragma unroll
    for (int q = 0; q < 4; ++q)
      #pragma unroll
      for (int mf = 0; mf < 2; ++mf) {
        const int f = wv * 32 + mf * 16 + lgrp * 4;
        if (f < F_) {
          float4 v;
          v.x = acc[q][mf][0] + bias;
          v.y = acc[q][mf][1] + bias;
          v.z = acc[q][mf][2] + bias;
          v.w = acc[q][mf][3] + bias;
          *(float4*)(out + (size_t)(bj0 + q) * (C_ * F_) + lrow * F_ + f) = v;
        }
      }
  }
}

extern "C" void kernel_launch(void* const* d_in, const int* in_sizes, int n_in,
                              void* d_out, int out_size, void* d_ws, size_t ws_size,
                              hipStream_t stream) {
  const float* z     = (const float*)d_in[0];
  const float* Wl    = (const float*)d_in[1];
  const float* bl    = (const float*)d_in[2];
  const float* joint = (const float*)d_in[3];
  const float* fe    = (const float*)d_in[4];
  const float* gamma = (const float*)d_in[5];
  const float* beta  = (const float*)d_in[6];
  const float* W1    = (const float*)d_in[7];
  const float* b1    = (const float*)d_in[8];
  const float* W2    = (const float*)d_in[9];
  const float* b2    = (const float*)d_in[10];
  float* out = (float*)d_out;

  char* ws = (char*)d_ws;
  float*          base  = (float*)(ws + 0);              // 32 KB
  unsigned short* W2T   = (unsigned short*)(ws + 32768); // 8 KB
  float*          bW1   = (float*)(ws + 40960);          // 1 KB
  float*          Sfe   = (float*)(ws + 41984);          // 0.5 KB
  float*          Sfe2  = (float*)(ws + 42496);          // 0.5 KB
  float*          Sc    = (float*)(ws + 43008);          // 18.5 KB
  float*          Sc2   = (float*)(ws + 61952);          // 18.5 KB
  float*          zerov = (float*)(ws + 80896);          // 1 KB
  unsigned short* BT    = (unsigned short*)(ws + 81920); // 384 KB
  float*          PX    = (float*)(ws + 8388608);        // 7.0 MB

  prep_kernel<<<157, 256, 0, stream>>>(z, Wl, bl, W1, gamma, beta, b1, fe, W2,
                                       base, BT, bW1, Sfe, Sfe2, W2T, zerov);
  gemmB_kernel<<<444, 256, 0, stream>>>(base, joint, fe, zerov, BT, PX, Sc, Sc2);
  mainC_kernel<<<M_ / 4, 256, 0, stream>>>(PX, bW1, Sc, Sc2, Sfe, Sfe2, W2T, b2, out);
}